// Round 1
// baseline (1041.255 us; speedup 1.0000x reference)
//
#include <hip/hip_runtime.h>
#include <hip/hip_bf16.h>
#include <stdint.h>

// ---------- helpers ----------
typedef __attribute__((ext_vector_type(8))) short short8v;   // 8 x bf16 bits (4 VGPRs)
typedef __attribute__((ext_vector_type(4))) float f32x4;

__device__ __forceinline__ unsigned short f2bf(float f) {
  unsigned u = __builtin_bit_cast(unsigned, f);
  unsigned r = 0x7fffu + ((u >> 16) & 1u);          // round-to-nearest-even
  return (unsigned short)((u + r) >> 16);
}
__device__ __forceinline__ float bf2f(unsigned short h) {
  unsigned u = ((unsigned)h) << 16;
  return __builtin_bit_cast(float, u);
}
__device__ __forceinline__ void gload_lds16(const void* g, void* l) {
  __builtin_amdgcn_global_load_lds(
      (const __attribute__((address_space(1))) void*)g,
      (__attribute__((address_space(3))) void*)l, 16, 0, 0);
}

// ---------- split kernels ----------
// x (row-major, no transpose): fp32 -> hi/lo bf16, same layout
__global__ __launch_bounds__(256) void split_plain(
    const float4* __restrict__ X, ushort4* __restrict__ H, ushort4* __restrict__ L, int n4) {
  int idx = blockIdx.x * 256 + threadIdx.x;
  if (idx >= n4) return;
  float4 v = X[idx];
  ushort4 h, l;
  h.x = f2bf(v.x); l.x = f2bf(v.x - bf2f(h.x));
  h.y = f2bf(v.y); l.y = f2bf(v.y - bf2f(h.y));
  h.z = f2bf(v.z); l.z = f2bf(v.z - bf2f(h.z));
  h.w = f2bf(v.w); l.w = f2bf(v.w - bf2f(h.w));
  H[idx] = h; L[idx] = l;
}

// W (Kd x Nd) fp32 -> transposed hi/lo bf16 (Nd x Kd), LDS-tiled 32x32
__global__ __launch_bounds__(256) void split_T(
    const float* __restrict__ W, unsigned short* __restrict__ H,
    unsigned short* __restrict__ L, int Kd, int Nd) {
  __shared__ float tile[32][33];
  const int t = threadIdx.x;
  const int c = t & 31;
  const int r0 = t >> 5;           // 0..7
  const int k0 = blockIdx.y * 32, n0 = blockIdx.x * 32;
#pragma unroll
  for (int i = 0; i < 4; ++i) {
    int r = r0 + i * 8;
    tile[r][c] = W[(size_t)(k0 + r) * Nd + n0 + c];
  }
  __syncthreads();
#pragma unroll
  for (int i = 0; i < 4; ++i) {
    int n = r0 + i * 8;
    float f = tile[c][n];          // = W[k0+c][n0+n]
    unsigned short h = f2bf(f);
    unsigned short l = f2bf(f - bf2f(h));
    size_t o = (size_t)(n0 + n) * Kd + k0 + c;
    H[o] = h; L[o] = l;
  }
}

// ---------- GEMM: C = sum_pass A_p @ B_p^T  (A: MxK, B: NxK, both bf16 row-major) ----------
// EPI 0: write fp32 C; 1: write bf16 C; 2: write split hi/lo bf16 (two buffers)
template<int EPI>
__global__ __launch_bounds__(256, 2) void gemm_bt(
    const unsigned short* __restrict__ A0, const unsigned short* __restrict__ B0,
    const unsigned short* __restrict__ A1, const unsigned short* __restrict__ B1,
    const unsigned short* __restrict__ A2, const unsigned short* __restrict__ B2,
    int npass, int M, int N, int K,
    float* __restrict__ Cf, unsigned short* __restrict__ Ch, unsigned short* __restrict__ Cl) {
  __shared__ unsigned short As[128 * 64];   // [row][k], 64-elem rows (128B)
  __shared__ unsigned short Bs[128 * 64];
  const int t = threadIdx.x;
  const int w = t >> 6;                 // wave 0..3
  const int lane = t & 63;
  const int wm = (w >> 1) * 64;         // wave tile origin in block
  const int wn = (w & 1) * 64;
  const int m0 = blockIdx.y * 128;
  const int n0 = blockIdx.x * 128;
  const int lr = lane & 15;             // frag own-dim index
  const int lk = (lane >> 4) * 8;       // frag k offset within 32
  const int rs = t >> 3;                // staging row 0..31
  const int cs = (t & 7) * 8;           // staging col (elements)

  f32x4 acc[4][4];
#pragma unroll
  for (int a = 0; a < 4; ++a)
#pragma unroll
    for (int b = 0; b < 4; ++b) acc[a][b] = {0.f, 0.f, 0.f, 0.f};

  for (int pass = 0; pass < npass; ++pass) {
    const unsigned short* A = (pass == 0) ? A0 : ((pass == 1) ? A1 : A2);
    const unsigned short* B = (pass == 0) ? B0 : ((pass == 1) ? B1 : B2);
    const unsigned short* ga = A + (size_t)(m0 + rs) * K + cs;
    const unsigned short* gb = B + (size_t)(n0 + rs) * K + cs;
    for (int k0 = 0; k0 < K; k0 += 64) {
#pragma unroll
      for (int i = 0; i < 4; ++i) {
        gload_lds16(ga + (size_t)(i * 32) * K + k0, &As[i * 2048 + w * 512]);
        gload_lds16(gb + (size_t)(i * 32) * K + k0, &Bs[i * 2048 + w * 512]);
      }
      __syncthreads();   // drains vmcnt -> tiles resident
#pragma unroll
      for (int kk = 0; kk < 2; ++kk) {
        short8v af[4], bf[4];
#pragma unroll
        for (int a = 0; a < 4; ++a)
          af[a] = *(const short8v*)&As[(wm + a * 16 + lr) * 64 + kk * 32 + lk];
#pragma unroll
        for (int b = 0; b < 4; ++b)
          bf[b] = *(const short8v*)&Bs[(wn + b * 16 + lr) * 64 + kk * 32 + lk];
#pragma unroll
        for (int a = 0; a < 4; ++a)
#pragma unroll
          for (int b = 0; b < 4; ++b)
            acc[a][b] = __builtin_amdgcn_mfma_f32_16x16x32_bf16(af[a], bf[b], acc[a][b], 0, 0, 0);
      }
      __syncthreads();   // all reads done before next-tile overwrite
    }
  }

  // epilogue: D elem r -> row=(lane>>4)*4+r, col=lane&15  [m89/m91-verified]
  const int crow = m0 + wm + (lane >> 4) * 4;
  const int ccol = n0 + wn + (lane & 15);
#pragma unroll
  for (int a = 0; a < 4; ++a)
#pragma unroll
    for (int r = 0; r < 4; ++r) {
      int row = crow + a * 16 + r;
#pragma unroll
      for (int b = 0; b < 4; ++b) {
        int col = ccol + b * 16;
        float f = acc[a][b][r];
        size_t o = (size_t)row * N + col;
        if (EPI == 0) {
          Cf[o] = f;
        } else if (EPI == 1) {
          Ch[o] = f2bf(f);
        } else {
          unsigned short h = f2bf(f);
          Ch[o] = h;
          Cl[o] = f2bf(f - bf2f(h));
        }
      }
    }
}

// ---------- row softmax: fp32 (n per row) -> bf16 p ----------
__global__ __launch_bounds__(256) void softmax_rows(
    const float* __restrict__ S, unsigned short* __restrict__ P, int n) {
  const int row = blockIdx.x;
  const int t = threadIdx.x;
  const float4* src = (const float4*)(S + (size_t)row * n);
  float4 v[4];
  float mx = -3.0e38f;
#pragma unroll
  for (int i = 0; i < 4; ++i) {
    v[i] = src[i * 256 + t];
    mx = fmaxf(mx, fmaxf(fmaxf(v[i].x, v[i].y), fmaxf(v[i].z, v[i].w)));
  }
#pragma unroll
  for (int off = 32; off; off >>= 1) mx = fmaxf(mx, __shfl_xor(mx, off));
  __shared__ float redm[4], reds[4];
  const int wid = t >> 6, lane = t & 63;
  if (lane == 0) redm[wid] = mx;
  __syncthreads();
  mx = fmaxf(fmaxf(redm[0], redm[1]), fmaxf(redm[2], redm[3]));
  float sum = 0.f;
#pragma unroll
  for (int i = 0; i < 4; ++i) {
    v[i].x = __expf(v[i].x - mx);
    v[i].y = __expf(v[i].y - mx);
    v[i].z = __expf(v[i].z - mx);
    v[i].w = __expf(v[i].w - mx);
    sum += (v[i].x + v[i].y) + (v[i].z + v[i].w);
  }
#pragma unroll
  for (int off = 32; off; off >>= 1) sum += __shfl_xor(sum, off);
  if (lane == 0) reds[wid] = sum;
  __syncthreads();
  sum = (reds[0] + reds[1]) + (reds[2] + reds[3]);
  float inv = 1.0f / sum;
#pragma unroll
  for (int i = 0; i < 4; ++i) {
    ushort4 o;
    o.x = f2bf(v[i].x * inv);
    o.y = f2bf(v[i].y * inv);
    o.z = f2bf(v[i].z * inv);
    o.w = f2bf(v[i].w * inv);
    *(ushort4*)(P + (size_t)row * n + (size_t)(i * 256 + t) * 4) = o;
  }
}

// ---------- launch ----------
extern "C" void kernel_launch(void* const* d_in, const int* in_sizes, int n_in,
                              void* d_out, int out_size, void* d_ws, size_t ws_size,
                              hipStream_t stream) {
  (void)in_sizes; (void)n_in; (void)out_size; (void)ws_size;
  const float* x  = (const float*)d_in[0];
  const float* Wq = (const float*)d_in[1];
  const float* Wk = (const float*)d_in[2];
  const float* Wv = (const float*)d_in[3];
  const int N = 4096, D = 1024;
  const size_t MB = 1ull << 20;
  char* ws = (char*)d_ws;
  // workspace layout (peak 192 MB; vT/p alias dead regions)
  unsigned short* xh  = (unsigned short*)(ws + 0 * MB);     // 8 MB
  unsigned short* xl  = (unsigned short*)(ws + 8 * MB);     // 8 MB
  unsigned short* wqh = (unsigned short*)(ws + 16 * MB);    // 8 MB
  unsigned short* wql = (unsigned short*)(ws + 24 * MB);    // 8 MB
  unsigned short* wkh = (unsigned short*)(ws + 32 * MB);    // 8 MB
  unsigned short* wkl = (unsigned short*)(ws + 40 * MB);    // 8 MB
  unsigned short* wvh = (unsigned short*)(ws + 48 * MB);    // 8 MB
  unsigned short* wvl = (unsigned short*)(ws + 56 * MB);    // 8 MB (written, unused)
  unsigned short* qh  = (unsigned short*)(ws + 64 * MB);    // 32 MB
  unsigned short* ql  = (unsigned short*)(ws + 96 * MB);    // 32 MB
  unsigned short* kh  = (unsigned short*)(ws + 128 * MB);   // 32 MB
  unsigned short* kl  = (unsigned short*)(ws + 160 * MB);   // 32 MB
  unsigned short* vT  = (unsigned short*)(ws + 16 * MB);    // 32 MB, over wq/wk splits (dead)
  unsigned short* p   = (unsigned short*)(ws + 64 * MB);    // 32 MB, over qh (dead)
  float* score = (float*)d_out;
  float* out   = (float*)d_out;

  // 1) splits
  split_plain<<<(N * D / 4 + 255) / 256, 256, 0, stream>>>(
      (const float4*)x, (ushort4*)xh, (ushort4*)xl, N * D / 4);
  dim3 gT(N / 32, D / 32);
  split_T<<<gT, 256, 0, stream>>>(Wq, wqh, wql, D, N);
  split_T<<<gT, 256, 0, stream>>>(Wk, wkh, wkl, D, N);
  split_T<<<gT, 256, 0, stream>>>(Wv, wvh, wvl, D, N);

  dim3 gg(N / 128, N / 128);
  // 2) q = x @ Wq (split, 3-pass, epilogue re-splits to hi/lo)
  gemm_bt<2><<<gg, 256, 0, stream>>>(xh, wqh, xl, wqh, xh, wql, 3, N, N, D,
                                     nullptr, qh, ql);
  // 3) k = x @ Wk
  gemm_bt<2><<<gg, 256, 0, stream>>>(xh, wkh, xl, wkh, xh, wkl, 3, N, N, D,
                                     nullptr, kh, kl);
  // 4) vT[n][i] = sum_d Wv[d][n] x[i][d]  (plain bf16, 1-pass) — overwrites wq/wk splits
  gemm_bt<1><<<gg, 256, 0, stream>>>(wvh, xh, nullptr, nullptr, nullptr, nullptr, 1, N, N, D,
                                     nullptr, vT, nullptr);
  // 5) score = q @ k^T (split, 3-pass, K=4096) -> fp32 in d_out
  gemm_bt<0><<<gg, 256, 0, stream>>>(qh, kh, ql, kh, qh, kl, 3, N, N, N,
                                     score, nullptr, nullptr);
  // 6) p = softmax(score) -> bf16, overwrites qh region
  softmax_rows<<<N, 256, 0, stream>>>(score, p, N);
  // 7) out = p @ v = p @ vT^T -> fp32 d_out
  gemm_bt<0><<<gg, 256, 0, stream>>>(p, vT, nullptr, nullptr, nullptr, nullptr, 1, N, N, N,
                                     out, nullptr, nullptr);
}

// Round 2
// 755.715 us; speedup vs baseline: 1.3778x; 1.3778x over previous
//
#include <hip/hip_runtime.h>
#include <hip/hip_bf16.h>
#include <stdint.h>

// ---------- helpers ----------
typedef __attribute__((ext_vector_type(8))) short short8v;   // 8 x bf16 bits (4 VGPRs)
typedef __attribute__((ext_vector_type(4))) float f32x4;

__device__ __forceinline__ unsigned short f2bf(float f) {
  unsigned u = __builtin_bit_cast(unsigned, f);
  unsigned r = 0x7fffu + ((u >> 16) & 1u);          // round-to-nearest-even
  return (unsigned short)((u + r) >> 16);
}
__device__ __forceinline__ float bf2f(unsigned short h) {
  unsigned u = ((unsigned)h) << 16;
  return __builtin_bit_cast(float, u);
}
__device__ __forceinline__ void gload_lds16(const void* g, void* l) {
  __builtin_amdgcn_global_load_lds(
      (const __attribute__((address_space(1))) void*)g,
      (__attribute__((address_space(3))) void*)l, 16, 0, 0);
}
#define SBAR  __builtin_amdgcn_s_barrier()
#define SCHED __builtin_amdgcn_sched_barrier(0)

// ---------- split kernels ----------
__global__ __launch_bounds__(256) void split_plain(
    const float4* __restrict__ X, ushort4* __restrict__ H, ushort4* __restrict__ L, int n4) {
  int idx = blockIdx.x * 256 + threadIdx.x;
  if (idx >= n4) return;
  float4 v = X[idx];
  ushort4 h, l;
  h.x = f2bf(v.x); l.x = f2bf(v.x - bf2f(h.x));
  h.y = f2bf(v.y); l.y = f2bf(v.y - bf2f(h.y));
  h.z = f2bf(v.z); l.z = f2bf(v.z - bf2f(h.z));
  h.w = f2bf(v.w); l.w = f2bf(v.w - bf2f(h.w));
  H[idx] = h; L[idx] = l;
}

__global__ __launch_bounds__(256) void split_T(
    const float* __restrict__ W, unsigned short* __restrict__ H,
    unsigned short* __restrict__ L, int Kd, int Nd) {
  __shared__ float tile[32][33];
  const int t = threadIdx.x;
  const int c = t & 31;
  const int r0 = t >> 5;
  const int k0 = blockIdx.y * 32, n0 = blockIdx.x * 32;
#pragma unroll
  for (int i = 0; i < 4; ++i) {
    int r = r0 + i * 8;
    tile[r][c] = W[(size_t)(k0 + r) * Nd + n0 + c];
  }
  __syncthreads();
#pragma unroll
  for (int i = 0; i < 4; ++i) {
    int n = r0 + i * 8;
    float f = tile[c][n];
    unsigned short h = f2bf(f);
    unsigned short l = f2bf(f - bf2f(h));
    size_t o = (size_t)(n0 + n) * Kd + k0 + c;
    H[o] = h; L[o] = l;
  }
}

// ---------- 256x256 8-phase GEMM: C = sum_pass A_p @ B_p^T ----------
// A: MxK, B: NxK, bf16 row-major. BK=32, 4-deep LDS ring, counted vmcnt,
// XOR slot swizzle (T2), setprio around MFMA (T5), XCD block swizzle (T1).
// EPI 0: fp32 C; 1: bf16 C; 2: split hi/lo bf16.
template<int EPI>
__global__ __launch_bounds__(512, 2) void gemm256(
    const unsigned short* __restrict__ A0, const unsigned short* __restrict__ B0,
    const unsigned short* __restrict__ A1, const unsigned short* __restrict__ B1,
    const unsigned short* __restrict__ A2, const unsigned short* __restrict__ B2,
    int npass, int N, int K,
    float* __restrict__ Cf, unsigned short* __restrict__ Ch, unsigned short* __restrict__ Cl) {
  // 4 slots x (A 8192 ush + B 8192 ush) = 65536 ush = 128 KiB
  __shared__ unsigned short lds[65536];
  const int NT = K >> 5;                       // K-tiles of 32 (NT % 4 == 0 here)
  // XCD-bijective swizzle for 256 workgroups (8 XCDs x 32)
  const int wg = blockIdx.x;
  const int sw = ((wg & 7) << 5) | (wg >> 3);
  const int bx = sw & 15, by = sw >> 4;
  const int m0 = by << 8, n0 = bx << 8;

  const int tid = threadIdx.x;
  const int w = tid >> 6, lane = tid & 63;
  const int wr = w >> 2, wc = w & 3;           // 2 x 4 wave grid; wave tile 128x64
  const int lr = lane & 15;
  // read-side swizzle: phys 16B-slot = logical ^ ((row>>1)&3); row bits1-2 = lr bits1-2
  const int phys = (lane >> 4) ^ ((lr >> 1) & 3);
  const int aoff = (wr * 128 + lr) * 32 + phys * 8;          // ush, + h*2048 + m*512
  const int boff = 8192 + (wc * 64 + lr) * 32 + phys * 8;    // ush, + n*512
  // stage-side: linear LDS dest, inverse-swizzled global source (Rule 21)
  const int rst = w * 16 + (lane >> 2);                      // source row, j=0
  const int ssrc = ((lane & 3) ^ ((lane >> 3) & 3)) * 8;     // source k-slot (elements)

  f32x4 acc[8][4];
#pragma unroll
  for (int m = 0; m < 8; ++m)
#pragma unroll
    for (int n = 0; n < 4; ++n) acc[m][n] = {0.f, 0.f, 0.f, 0.f};

  for (int pass = 0; pass < npass; ++pass) {
    const unsigned short* A = (pass == 0) ? A0 : ((pass == 1) ? A1 : A2);
    const unsigned short* B = (pass == 0) ? B0 : ((pass == 1) ? B1 : B2);
    const unsigned short* gA = A + (size_t)(m0 + rst) * K + ssrc;
    const unsigned short* gB = B + (size_t)(n0 + rst) * K + ssrc;
    const size_t jstep = (size_t)128 * K;

    SCHED; SBAR; SCHED;                 // previous pass/tile reads complete
    // prologue: stage tiles 0..2 into slots 0..2
#pragma unroll
    for (int tau = 0; tau < 3; ++tau) {
      const int so = tau * 16384 + (w << 9);
      gload_lds16(gA + (size_t)tau * 32, &lds[so]);
      gload_lds16(gA + (size_t)tau * 32 + jstep, &lds[so + 4096]);
      gload_lds16(gB + (size_t)tau * 32, &lds[so + 8192]);
      gload_lds16(gB + (size_t)tau * 32 + jstep, &lds[so + 12288]);
    }
    asm volatile("s_waitcnt vmcnt(8)"); // tile 0 landed; 1,2 in flight
    SCHED; SBAR; SCHED;

    for (int t = 0; t < NT; ++t) {
      const int sb = (t & 3) * 16384;
      const bool st = (t + 3) < NT;
      short8v bfr[4], af[4];
      // ---- phase 0: B frags + A frags (m 0-3), stage A(t+3), 16 MFMA ----
#pragma unroll
      for (int n = 0; n < 4; ++n)
        bfr[n] = *(const short8v*)&lds[sb + boff + n * 512];
#pragma unroll
      for (int m = 0; m < 4; ++m)
        af[m] = *(const short8v*)&lds[sb + aoff + m * 512];
      if (st) {
        const int so = ((t + 3) & 3) * 16384 + (w << 9);
        const unsigned short* src = gA + (size_t)(t + 3) * 32;
        gload_lds16(src, &lds[so]);
        gload_lds16(src + jstep, &lds[so + 4096]);
      }
      __builtin_amdgcn_s_setprio(1);
#pragma unroll
      for (int m = 0; m < 4; ++m)
#pragma unroll
        for (int n = 0; n < 4; ++n)
          acc[m][n] = __builtin_amdgcn_mfma_f32_16x16x32_bf16(af[m], bfr[n], acc[m][n], 0, 0, 0);
      __builtin_amdgcn_s_setprio(0);
      SCHED; SBAR; SCHED;
      // ---- phase 1: A frags (m 4-7), stage B(t+3), 16 MFMA ----
#pragma unroll
      for (int m = 0; m < 4; ++m)
        af[m] = *(const short8v*)&lds[sb + aoff + 2048 + m * 512];
      if (st) {
        const int so = ((t + 3) & 3) * 16384 + 8192 + (w << 9);
        const unsigned short* src = gB + (size_t)(t + 3) * 32;
        gload_lds16(src, &lds[so]);
        gload_lds16(src + jstep, &lds[so + 4096]);
      }
      __builtin_amdgcn_s_setprio(1);
#pragma unroll
      for (int m = 0; m < 4; ++m)
#pragma unroll
        for (int n = 0; n < 4; ++n)
          acc[4 + m][n] = __builtin_amdgcn_mfma_f32_16x16x32_bf16(af[m], bfr[n], acc[4 + m][n], 0, 0, 0);
      __builtin_amdgcn_s_setprio(0);
      SCHED;
      // ---- tile boundary: counted vmcnt (never drains the pipeline mid-loop) ----
      if (t < NT - 3)       { asm volatile("s_waitcnt vmcnt(8)"); }
      else if (t == NT - 3) { asm volatile("s_waitcnt vmcnt(4)"); }
      else if (t == NT - 2) { asm volatile("s_waitcnt vmcnt(0)"); }
      SCHED;
      if (t < NT - 1) { SBAR; SCHED; }
    }
  }

  // epilogue: frag r -> row=(lane>>4)*4+r, col=lane&15  [m89/m91-verified]
  const int crow = m0 + wr * 128 + ((lane >> 4) << 2);
  const int ccol = n0 + wc * 64 + lr;
#pragma unroll
  for (int mi = 0; mi < 8; ++mi)
#pragma unroll
    for (int r = 0; r < 4; ++r) {
      const int row = crow + mi * 16 + r;
#pragma unroll
      for (int n = 0; n < 4; ++n) {
        const int col = ccol + n * 16;
        const float f = acc[mi][n][r];
        const size_t o = (size_t)row * N + col;
        if (EPI == 0) {
          Cf[o] = f;
        } else if (EPI == 1) {
          Ch[o] = f2bf(f);
        } else {
          const unsigned short h = f2bf(f);
          Ch[o] = h;
          Cl[o] = f2bf(f - bf2f(h));
        }
      }
    }
}

// ---------- row softmax: fp32 (n per row) -> bf16 p ----------
__global__ __launch_bounds__(256) void softmax_rows(
    const float* __restrict__ S, unsigned short* __restrict__ P, int n) {
  const int row = blockIdx.x;
  const int t = threadIdx.x;
  const float4* src = (const float4*)(S + (size_t)row * n);
  float4 v[4];
  float mx = -3.0e38f;
#pragma unroll
  for (int i = 0; i < 4; ++i) {
    v[i] = src[i * 256 + t];
    mx = fmaxf(mx, fmaxf(fmaxf(v[i].x, v[i].y), fmaxf(v[i].z, v[i].w)));
  }
#pragma unroll
  for (int off = 32; off; off >>= 1) mx = fmaxf(mx, __shfl_xor(mx, off));
  __shared__ float redm[4], reds[4];
  const int wid = t >> 6, lane = t & 63;
  if (lane == 0) redm[wid] = mx;
  __syncthreads();
  mx = fmaxf(fmaxf(redm[0], redm[1]), fmaxf(redm[2], redm[3]));
  float sum = 0.f;
#pragma unroll
  for (int i = 0; i < 4; ++i) {
    v[i].x = __expf(v[i].x - mx);
    v[i].y = __expf(v[i].y - mx);
    v[i].z = __expf(v[i].z - mx);
    v[i].w = __expf(v[i].w - mx);
    sum += (v[i].x + v[i].y) + (v[i].z + v[i].w);
  }
#pragma unroll
  for (int off = 32; off; off >>= 1) sum += __shfl_xor(sum, off);
  if (lane == 0) reds[wid] = sum;
  __syncthreads();
  sum = (reds[0] + reds[1]) + (reds[2] + reds[3]);
  float inv = 1.0f / sum;
#pragma unroll
  for (int i = 0; i < 4; ++i) {
    ushort4 o;
    o.x = f2bf(v[i].x * inv);
    o.y = f2bf(v[i].y * inv);
    o.z = f2bf(v[i].z * inv);
    o.w = f2bf(v[i].w * inv);
    *(ushort4*)(P + (size_t)row * n + (size_t)(i * 256 + t) * 4) = o;
  }
}

// ---------- launch ----------
extern "C" void kernel_launch(void* const* d_in, const int* in_sizes, int n_in,
                              void* d_out, int out_size, void* d_ws, size_t ws_size,
                              hipStream_t stream) {
  (void)in_sizes; (void)n_in; (void)out_size; (void)ws_size;
  const float* x  = (const float*)d_in[0];
  const float* Wq = (const float*)d_in[1];
  const float* Wk = (const float*)d_in[2];
  const float* Wv = (const float*)d_in[3];
  const int N = 4096, D = 1024;
  const size_t MB = 1ull << 20;
  char* ws = (char*)d_ws;
  unsigned short* xh  = (unsigned short*)(ws + 0 * MB);     // 8 MB
  unsigned short* xl  = (unsigned short*)(ws + 8 * MB);     // 8 MB
  unsigned short* wqh = (unsigned short*)(ws + 16 * MB);    // 8 MB
  unsigned short* wql = (unsigned short*)(ws + 24 * MB);    // 8 MB
  unsigned short* wkh = (unsigned short*)(ws + 32 * MB);    // 8 MB
  unsigned short* wkl = (unsigned short*)(ws + 40 * MB);    // 8 MB
  unsigned short* wvh = (unsigned short*)(ws + 48 * MB);    // 8 MB
  unsigned short* wvl = (unsigned short*)(ws + 56 * MB);    // 8 MB (written, unused)
  unsigned short* qh  = (unsigned short*)(ws + 64 * MB);    // 32 MB
  unsigned short* ql  = (unsigned short*)(ws + 96 * MB);    // 32 MB
  unsigned short* kh  = (unsigned short*)(ws + 128 * MB);   // 32 MB
  unsigned short* kl  = (unsigned short*)(ws + 160 * MB);   // 32 MB
  unsigned short* vT  = (unsigned short*)(ws + 16 * MB);    // 32 MB, over wq/wk splits (dead)
  unsigned short* p   = (unsigned short*)(ws + 64 * MB);    // 32 MB, over qh (dead)
  float* score = (float*)d_out;
  float* out   = (float*)d_out;

  // 1) splits
  split_plain<<<(N * D / 4 + 255) / 256, 256, 0, stream>>>(
      (const float4*)x, (ushort4*)xh, (ushort4*)xl, N * D / 4);
  dim3 gT(N / 32, D / 32);
  split_T<<<gT, 256, 0, stream>>>(Wq, wqh, wql, D, N);
  split_T<<<gT, 256, 0, stream>>>(Wk, wkh, wkl, D, N);
  split_T<<<gT, 256, 0, stream>>>(Wv, wvh, wvl, D, N);

  const int GG = (N / 256) * (N / 256);   // 256 workgroups
  // 2) q = x @ Wq (3-pass split, epilogue re-splits hi/lo)
  gemm256<2><<<GG, 512, 0, stream>>>(xh, wqh, xl, wqh, xh, wql, 3, N, D,
                                     nullptr, qh, ql);
  // 3) k = x @ Wk
  gemm256<2><<<GG, 512, 0, stream>>>(xh, wkh, xl, wkh, xh, wkl, 3, N, D,
                                     nullptr, kh, kl);
  // 4) vT = (x @ Wv)^T  (plain bf16, 1-pass)
  gemm256<1><<<GG, 512, 0, stream>>>(wvh, xh, nullptr, nullptr, nullptr, nullptr, 1, N, D,
                                     nullptr, vT, nullptr);
  // 5) score = q @ k^T (3-pass split, K=4096) -> fp32 d_out
  gemm256<0><<<GG, 512, 0, stream>>>(qh, kh, ql, kh, qh, kl, 3, N, N,
                                     score, nullptr, nullptr);
  // 6) p = softmax(score) -> bf16
  softmax_rows<<<N, 256, 0, stream>>>(score, p, N);
  // 7) out = p @ vT^T -> fp32 d_out
  gemm256<0><<<GG, 512, 0, stream>>>(p, vT, nullptr, nullptr, nullptr, nullptr, 1, N, N,
                                     out, nullptr, nullptr);
}